// Round 1
// baseline (243.031 us; speedup 1.0000x reference)
//
#include <hip/hip_runtime.h>

#define B_ 16
#define N_ 1024
#define C_ 768
#define E_ 8
#define H_ 192
#define K_ 2

typedef __bf16 bf16x8 __attribute__((ext_vector_type(8)));
typedef float  f32x4  __attribute__((ext_vector_type(4)));

// ---------------------------------------------------------------------------
// Kernel 1: convert fc1_w / fc2_w (each E*H*C f32) to bf16 in workspace.
// ---------------------------------------------------------------------------
__global__ __launch_bounds__(256) void convert_w_kernel(
    const float* __restrict__ w1, const float* __restrict__ w2,
    __bf16* __restrict__ w1b, __bf16* __restrict__ w2b) {
  int idx = blockIdx.x * 256 + threadIdx.x;            // float4 index
  const int n4 = (E_ * H_ * C_) / 4;                   // 294912
  if (idx >= n4) return;
  float4 a = *(const float4*)(w1 + (size_t)idx * 4);
  float4 b = *(const float4*)(w2 + (size_t)idx * 4);
  __bf16* d1 = w1b + (size_t)idx * 4;
  __bf16* d2 = w2b + (size_t)idx * 4;
  d1[0] = (__bf16)a.x; d1[1] = (__bf16)a.y; d1[2] = (__bf16)a.z; d1[3] = (__bf16)a.w;
  d2[0] = (__bf16)b.x; d2[1] = (__bf16)b.y; d2[2] = (__bf16)b.z; d2[3] = (__bf16)b.w;
}

// ---------------------------------------------------------------------------
// Kernel 2: gating. Grid = B*32 blocks, each block = 32 tokens of one b.
// Computes logits (f32) and atomically accumulates exp_wise_sum[b][e].
// ---------------------------------------------------------------------------
__global__ __launch_bounds__(256) void gate_kernel(
    const float* __restrict__ x, const int* __restrict__ task_ids,
    const float* __restrict__ eps, const float* __restrict__ gate_w,
    float* __restrict__ sums) {
  const int b = blockIdx.x >> 5;
  const int tile = blockIdx.x & 31;
  const int token0 = tile * 32;
  const int tid = threadIdx.x;

  // gate_w[task] transposed into LDS: gwt[j][c], row stride 772 (pad 4) to
  // break the 16-way bank aliasing of stride-768 rows.
  __shared__ __align__(16) float gwt[16][772];
  __shared__ float sc[16][16];
  __shared__ float red[16][8];

  const int task = task_ids[b];
  const float* gw = gate_w + (size_t)task * C_ * 16;
  for (int it = 0; it < 12; ++it) {
    int idx4 = it * 256 + tid;                 // 0..3071
    float4 v = *(const float4*)(gw + (size_t)idx4 * 4);
    int flat = idx4 * 4;                       // = c*16 + j, j in {0,4,8,12}
    int c = flat >> 4;
    int j = flat & 15;
    gwt[j + 0][c] = v.x; gwt[j + 1][c] = v.y;
    gwt[j + 2][c] = v.z; gwt[j + 3][c] = v.w;
  }
  __syncthreads();

  const int j = tid & 15;
  const int tslot = tid >> 4;
  float part = 0.0f;
  for (int pass = 0; pass < 2; ++pass) {
    const int t = pass * 16 + tslot;
    const int n = token0 + t;
    const float* xr = x + ((size_t)b * N_ + n) * C_;
    float acc = 0.0f;
#pragma unroll 4
    for (int c = 0; c < C_; c += 4) {
      float4 xv = *(const float4*)(xr + c);
      float4 wv = *(const float4*)&gwt[j][c];
      acc += xv.x * wv.x + xv.y * wv.y + xv.z * wv.z + xv.w * wv.w;
    }
    sc[tslot][j] = acc;
    __syncthreads();
    if (j < 8) {
      float clean = sc[tslot][j];
      float raw = sc[tslot][j + 8];
      float sp = (raw > 20.0f) ? raw : log1pf(expf(raw));
      float lg = clean + eps[((size_t)b * N_ + n) * E_ + j] * (sp + 0.01f);
      part += lg;
    }
    __syncthreads();
  }
  if (j < 8) red[tslot][j] = part;
  __syncthreads();
  if (tid < 8) {
    float s = 0.0f;
#pragma unroll
    for (int t = 0; t < 16; ++t) s += red[t][tid];
    atomicAdd(&sums[b * E_ + tid], s);
  }
}

// ---------------------------------------------------------------------------
// Kernel 3: top-2 + gate values per b. One tiny block.
// Tie behavior matches jax.lax.top_k (stable descending: strict >).
// ---------------------------------------------------------------------------
__global__ __launch_bounds__(64) void topk_kernel(
    const float* __restrict__ sums, int* __restrict__ tk_idx,
    float* __restrict__ tk_gate) {
  int tid = threadIdx.x;
  if (tid >= B_) return;
  const float* s = sums + tid * E_;
  float best = -INFINITY, best2 = -INFINITY;
  int i1 = 0, i2 = 0;
#pragma unroll
  for (int e = 0; e < E_; ++e) {
    float v = s[e];
    if (v > best) { best2 = best; i2 = i1; best = v; i1 = e; }
    else if (v > best2) { best2 = v; i2 = e; }
  }
  // scaled = (v - min)/(max - min + 1e-6): top -> d/(d+1e-6), bottom -> 0
  float d = best - best2;
  float st = d / (d + 1e-6f);
  float et = expf(st);
  tk_idx[tid * 2 + 0] = i1; tk_gate[tid * 2 + 0] = et / (et + 1.0f);
  tk_idx[tid * 2 + 1] = i2; tk_gate[tid * 2 + 1] = 1.0f / (et + 1.0f);
}

// ---------------------------------------------------------------------------
// Kernel 4: fused 2-expert adapter. Grid = B*32 blocks x 256 threads.
// Per block: 32 tokens. GEMM1 (32x192x768) -> bias+gelu*gate -> LDS ->
// GEMM2 (32x768x192) accumulated across both experts -> out = x + acc.
// MFMA 16x16x32 bf16. A-frag: A[m=lane&15][k=(lane>>4)*8+j].
// C/D: col = lane&15, row = (lane>>4)*4 + reg (verified m89/m91).
// ---------------------------------------------------------------------------
__global__ __launch_bounds__(256, 2) void expert_kernel(
    const float* __restrict__ x, const __bf16* __restrict__ w1b,
    const __bf16* __restrict__ w2b, const float* __restrict__ fc1_b,
    const float* __restrict__ fc2_b, const int* __restrict__ tk_idx,
    const float* __restrict__ tk_gate, float* __restrict__ out) {
  const int b = blockIdx.x >> 5;
  const int tile = blockIdx.x & 31;
  const int token0 = tile * 32;
  const int tid = threadIdx.x;
  const int wave = tid >> 6;
  const int lane = tid & 63;
  const int ln = lane & 15;
  const int q8 = (lane >> 4) * 8;
  const int q4 = (lane >> 4) * 4;

  // LDS: x tile bf16 (pad 768->776: row stride 1552B = 388 dwords == 4 mod 32
  // -> 2-way bank alias on A-frag b128 reads = free). h tile 192->200 same.
  __shared__ __align__(16) __bf16 xs[32][776];   // 49664 B
  __shared__ __align__(16) __bf16 hs[32][200];   // 12800 B

  int e_idx[2]; float gate_v[2];
  e_idx[0] = tk_idx[b * 2 + 0]; e_idx[1] = tk_idx[b * 2 + 1];
  gate_v[0] = tk_gate[b * 2 + 0]; gate_v[1] = tk_gate[b * 2 + 1];

  // stage x tile (f32 -> bf16). 32*768 = 6144 float4, 24 per thread.
  const float* xbase = x + ((size_t)b * N_ + token0) * C_;
  for (int it = 0; it < 24; ++it) {
    int chunk = it * 256 + tid;            // 0..6143
    int row = chunk / 192;                 // 192 float4 per row
    int col4 = chunk - row * 192;
    float4 v = *(const float4*)(xbase + (size_t)row * C_ + col4 * 4);
    __bf16* d = &xs[row][col4 * 4];
    d[0] = (__bf16)v.x; d[1] = (__bf16)v.y; d[2] = (__bf16)v.z; d[3] = (__bf16)v.w;
  }
  __syncthreads();

  f32x4 c2[2][12] = {};   // persistent y accumulator (gate folded into h)

  for (int kx = 0; kx < 2; ++kx) {
    const int e = e_idx[kx];
    const float g = gate_v[kx];

    // ---- GEMM1: h = x @ W1^T. waves split N=192 into 4x48.
    const __bf16* w1p = w1b + (size_t)e * H_ * C_;
    f32x4 c1[2][3] = {};
    for (int k0 = 0; k0 < C_; k0 += 32) {
      bf16x8 a0 = *(const bf16x8*)&xs[ln][k0 + q8];
      bf16x8 a1 = *(const bf16x8*)&xs[16 + ln][k0 + q8];
#pragma unroll
      for (int j = 0; j < 3; ++j) {
        int n = (wave * 3 + j) * 16 + ln;
        bf16x8 bv = *(const bf16x8*)(w1p + (size_t)n * C_ + k0 + q8);
        c1[0][j] = __builtin_amdgcn_mfma_f32_16x16x32_bf16(a0, bv, c1[0][j], 0, 0, 0);
        c1[1][j] = __builtin_amdgcn_mfma_f32_16x16x32_bf16(a1, bv, c1[1][j], 0, 0, 0);
      }
    }
    // bias + exact gelu + gate scale -> hs (bf16)
#pragma unroll
    for (int j = 0; j < 3; ++j) {
      int col = (wave * 3 + j) * 16 + ln;
      float b1 = fc1_b[e * H_ + col];
#pragma unroll
      for (int m = 0; m < 2; ++m) {
#pragma unroll
        for (int r = 0; r < 4; ++r) {
          int row = m * 16 + q4 + r;
          float v = c1[m][j][r] + b1;
          float gl = 0.5f * v * (1.0f + erff(v * 0.70710678118f));
          hs[row][col] = (__bf16)(g * gl);
        }
      }
    }
    __syncthreads();

    // ---- GEMM2: y += (g*gelu(h)) @ W2^T. waves split N=768 into 4x192.
    const __bf16* w2p = w2b + (size_t)e * C_ * H_;
    for (int k0 = 0; k0 < H_; k0 += 32) {
      bf16x8 a0 = *(const bf16x8*)&hs[ln][k0 + q8];
      bf16x8 a1 = *(const bf16x8*)&hs[16 + ln][k0 + q8];
#pragma unroll
      for (int j = 0; j < 12; ++j) {
        int n = (wave * 12 + j) * 16 + ln;
        bf16x8 bv = *(const bf16x8*)(w2p + (size_t)n * H_ + k0 + q8);
        c2[0][j] = __builtin_amdgcn_mfma_f32_16x16x32_bf16(a0, bv, c2[0][j], 0, 0, 0);
        c2[1][j] = __builtin_amdgcn_mfma_f32_16x16x32_bf16(a1, bv, c2[1][j], 0, 0, 0);
      }
    }
    __syncthreads();   // protect hs before next expert overwrites
  }

  // epilogue: out = x + y (+ gate-weighted fc2_b)
  const float* xr = x + ((size_t)b * N_ + token0) * C_;
  float* outr = out + ((size_t)b * N_ + token0) * C_;
#pragma unroll
  for (int j = 0; j < 12; ++j) {
    int col = (wave * 12 + j) * 16 + ln;
    float b2t = gate_v[0] * fc2_b[e_idx[0] * C_ + col] +
                gate_v[1] * fc2_b[e_idx[1] * C_ + col];
#pragma unroll
    for (int m = 0; m < 2; ++m) {
#pragma unroll
      for (int r = 0; r < 4; ++r) {
        int row = m * 16 + q4 + r;
        size_t off = (size_t)row * C_ + col;
        outr[off] = xr[off] + c2[m][j][r] + b2t;
      }
    }
  }
}

// ---------------------------------------------------------------------------
extern "C" void kernel_launch(void* const* d_in, const int* in_sizes, int n_in,
                              void* d_out, int out_size, void* d_ws, size_t ws_size,
                              hipStream_t stream) {
  const float* x      = (const float*)d_in[0];
  const int*   task   = (const int*)d_in[1];
  const float* eps    = (const float*)d_in[2];
  const float* gate_w = (const float*)d_in[3];
  const float* fc1_w  = (const float*)d_in[4];
  const float* fc1_b  = (const float*)d_in[5];
  const float* fc2_w  = (const float*)d_in[6];
  const float* fc2_b  = (const float*)d_in[7];
  float* out = (float*)d_out;

  // workspace layout (all offsets 256-aligned; ~4.7 MB total)
  const size_t nW = (size_t)E_ * H_ * C_;          // 1179648
  __bf16* w1b = (__bf16*)d_ws;
  __bf16* w2b = w1b + nW;
  float* sums = (float*)((char*)d_ws + 2 * nW * sizeof(__bf16));  // 4718592
  int* tk_idx = (int*)((char*)sums + 512);
  float* tk_gate = (float*)((char*)tk_idx + 256);

  hipMemsetAsync(sums, 0, B_ * E_ * sizeof(float), stream);
  convert_w_kernel<<<(nW / 4 + 255) / 256, 256, 0, stream>>>(fc1_w, fc2_w, w1b, w2b);
  gate_kernel<<<B_ * 32, 256, 0, stream>>>(x, task, eps, gate_w, sums);
  topk_kernel<<<1, 64, 0, stream>>>(sums, tk_idx, tk_gate);
  expert_kernel<<<B_ * 32, 256, 0, stream>>>(x, w1b, w2b, fc1_b, fc2_b,
                                             tk_idx, tk_gate, out);
}

// Round 3
// 209.853 us; speedup vs baseline: 1.1581x; 1.1581x over previous
//
#include <hip/hip_runtime.h>

#define B_ 16
#define N_ 1024
#define C_ 768
#define E_ 8
#define H_ 192
#define K_ 2

typedef __bf16 bf16x8 __attribute__((ext_vector_type(8)));
typedef float  f32x4  __attribute__((ext_vector_type(4)));

// ---------------------------------------------------------------------------
// Kernel 1: prep. (a) pack fc1_w/fc2_w to bf16 in MFMA-B-fragment order:
//   pw1[e][kb=c/32][n=h][c%32], pw2[e][kb=h/32][n=c][h%32]
//   -> a wave's B-loads per k-block become fully-contiguous 1KB reads.
// (b) transpose gate_w to gwT[d][j][c] (f32) for broadcast-friendly gating.
// ---------------------------------------------------------------------------
__global__ __launch_bounds__(256) void prep_kernel(
    const float* __restrict__ w1, const float* __restrict__ w2,
    const float* __restrict__ gw,
    __bf16* __restrict__ pw1, __bf16* __restrict__ pw2,
    float* __restrict__ gwT) {
  int idx = blockIdx.x * 256 + threadIdx.x;            // float4 index
  const int nW4 = (E_ * H_ * C_) / 4;                  // 294912
  if (idx >= nW4) return;
  int flat = idx * 4;
  int e = flat / (H_ * C_);
  int r = flat - e * (H_ * C_);

  // w1: [e][h][c] -> pw1
  {
    float4 a = *(const float4*)(w1 + (size_t)flat);
    int n = r / C_;           // h
    int c = r - n * C_;       // c, %4==0 (stays within one 32-chunk)
    size_t o = ((size_t)(e * 24 + (c >> 5)) * 192 + n) * 32 + (c & 31);
    pw1[o + 0] = (__bf16)a.x; pw1[o + 1] = (__bf16)a.y;
    pw1[o + 2] = (__bf16)a.z; pw1[o + 3] = (__bf16)a.w;
  }
  // w2: [e][c][h] -> pw2
  {
    float4 a = *(const float4*)(w2 + (size_t)flat);
    int n = r / H_;           // c index 0..767
    int h = r - n * H_;       // 0..191, %4==0
    size_t o = ((size_t)(e * 6 + (h >> 5)) * 768 + n) * 32 + (h & 31);
    pw2[o + 0] = (__bf16)a.x; pw2[o + 1] = (__bf16)a.y;
    pw2[o + 2] = (__bf16)a.z; pw2[o + 3] = (__bf16)a.w;
  }
  // gwT: [d][c][16] -> [d][j][c]  (tiny: 4*16*768 floats)
  if (idx < (4 * 16 * C_) / 4) {
    int f = idx * 4;
    int d = f / (16 * C_);
    int rr = f - d * (16 * C_);
    int j = rr / C_;
    int c = rr - j * C_;      // %4==0
    const float* src = gw + (size_t)d * C_ * 16 + j;
    float4 v;
    v.x = src[(size_t)(c + 0) * 16]; v.y = src[(size_t)(c + 1) * 16];
    v.z = src[(size_t)(c + 2) * 16]; v.w = src[(size_t)(c + 3) * 16];
    *(float4*)(gwT + (size_t)f) = v;
  }
}

// ---------------------------------------------------------------------------
// Kernel 2: gating. Grid = B*64 blocks, 16 tokens each, 256 thr.
// x tile staged coalesced into LDS (f32, exact); gwT broadcast-read from
// global (L2-hot, 16 lanes same address = 1 request). Thread = (token,j).
// ---------------------------------------------------------------------------
__global__ __launch_bounds__(256, 3) void gate_kernel(
    const float* __restrict__ x, const int* __restrict__ task_ids,
    const float* __restrict__ eps, const float* __restrict__ gwT,
    float* __restrict__ sums) {
  const int b = blockIdx.x >> 6;
  const int token0 = (blockIdx.x & 63) * 16;
  const int tid = threadIdx.x;

  __shared__ __align__(16) float xt[16][772];   // pad 4: stride%32==4 -> free
  __shared__ float sc[16][16];
  __shared__ float red[16][8];

  // stage 16x768 f32, coalesced: 3072 float4 / 256 thr = 12 each
  const float* xbase = x + ((size_t)b * N_ + token0) * C_;
  for (int it = 0; it < 12; ++it) {
    int chunk = it * 256 + tid;                 // 0..3071
    int row = chunk / 192;
    int col4 = chunk - row * 192;
    float4 v = *(const float4*)(xbase + (size_t)row * C_ + col4 * 4);
    *(float4*)&xt[row][col4 * 4] = v;
  }
  __syncthreads();

  const int t = tid & 15;
  const int j = tid >> 4;                       // 16 lanes share one j
  const int task = task_ids[b];
  const float* wrow = gwT + ((size_t)task * 16 + j) * C_;
  float acc = 0.0f;
#pragma unroll 4
  for (int c = 0; c < C_; c += 4) {
    float4 xv = *(const float4*)&xt[t][c];
    float4 wv = *(const float4*)(wrow + c);
    acc += xv.x * wv.x + xv.y * wv.y + xv.z * wv.z + xv.w * wv.w;
  }
  sc[t][j] = acc;
  __syncthreads();
  if (j < 8) {
    float clean = sc[t][j];
    float raw = sc[t][j + 8];
    float sp = (raw > 20.0f) ? raw : log1pf(expf(raw));
    float lg = clean + eps[((size_t)b * N_ + token0 + t) * E_ + j] * (sp + 0.01f);
    red[t][j] = lg;
  }
  __syncthreads();
  if (tid < 8) {
    float s = 0.0f;
#pragma unroll
    for (int tt = 0; tt < 16; ++tt) s += red[tt][tid];
    atomicAdd(&sums[b * E_ + tid], s);
  }
}

// ---------------------------------------------------------------------------
// Kernel 3: fused top-2 + 2-expert adapter. Grid = B*32 blocks x 256 thr.
// GEMM1: ping-pong over 24 k-blocks. GEMM2: flat 12-step pipeline
// (6 kb x 2 half-tiles); B buffer alternates by step parity, A buffer by
// kb parity (prefetched into the NOT-in-use buffer on odd steps only).
// MFMA 16x16x32 bf16; C/D: col=lane&15, row=(lane>>4)*4+reg.
// ---------------------------------------------------------------------------
__global__ __launch_bounds__(256, 2) void expert_kernel(
    const float* __restrict__ x, const __bf16* __restrict__ pw1,
    const __bf16* __restrict__ pw2, const float* __restrict__ fc1_b,
    const float* __restrict__ fc2_b, const float* __restrict__ sums,
    float* __restrict__ out) {
  const int b = blockIdx.x >> 5;
  const int token0 = (blockIdx.x & 31) * 32;
  const int tid = threadIdx.x;
  const int wave = tid >> 6;
  const int lane = tid & 63;
  const int ln = lane & 15;
  const int q8 = (lane >> 4) * 8;
  const int q4 = (lane >> 4) * 4;

  __shared__ __align__(16) __bf16 xs[32][776];   // 49664 B (stride%32dw==4)
  __shared__ __align__(16) __bf16 hs[32][200];   // 12800 B

  // inline top-2 (tie rule matches lax.top_k: strict >, stable)
  int e_idx[2]; float gate_v[2];
  {
    const float* s = sums + b * E_;
    float best = -INFINITY, best2 = -INFINITY;
    int i1 = 0, i2 = 0;
#pragma unroll
    for (int e = 0; e < E_; ++e) {
      float v = s[e];
      if (v > best) { best2 = best; i2 = i1; best = v; i1 = e; }
      else if (v > best2) { best2 = v; i2 = e; }
    }
    float d = best - best2;
    float st = d / (d + 1e-6f);
    float et = expf(st);
    e_idx[0] = i1; gate_v[0] = et / (et + 1.0f);
    e_idx[1] = i2; gate_v[1] = 1.0f / (et + 1.0f);
  }

  // stage x tile f32->bf16: 3072 chunks of 8 floats, 12 per thread, b128 LDS
  const float* xbase = x + ((size_t)b * N_ + token0) * C_;
  for (int it = 0; it < 12; ++it) {
    int chunk = it * 256 + tid;                 // 0..3071
    int row = chunk / 96;                       // 96 8-float chunks per row
    int col8 = chunk - row * 96;
    const float* p = xbase + (size_t)row * C_ + col8 * 8;
    float4 v0 = *(const float4*)p;
    float4 v1 = *(const float4*)(p + 4);
    bf16x8 t;
    t[0] = (__bf16)v0.x; t[1] = (__bf16)v0.y; t[2] = (__bf16)v0.z; t[3] = (__bf16)v0.w;
    t[4] = (__bf16)v1.x; t[5] = (__bf16)v1.y; t[6] = (__bf16)v1.z; t[7] = (__bf16)v1.w;
    *(bf16x8*)&xs[row][col8 * 8] = t;
  }
  __syncthreads();

  f32x4 c2[2][12] = {};   // persistent y accumulator (gate folded into h)

  for (int kx = 0; kx < 2; ++kx) {
    const int e = e_idx[kx];
    const float g = gate_v[kx];

    // ---- GEMM1: h = x @ W1^T, waves split H=192 into 4x48, K=768 (24 kb)
    const __bf16* w1l = pw1 + (size_t)e * (24 * 192 * 32)
                            + (size_t)(wave * 48 + ln) * 32 + q8;
    bf16x8 bq[2][3], aq[2][2];
#pragma unroll
    for (int j = 0; j < 3; ++j) bq[0][j] = *(const bf16x8*)(w1l + j * 512);
    aq[0][0] = *(const bf16x8*)&xs[ln][q8];
    aq[0][1] = *(const bf16x8*)&xs[16 + ln][q8];
    f32x4 c1[2][3] = {};
#pragma unroll
    for (int kb = 0; kb < 24; ++kb) {
      int p = kb & 1;
      if (kb < 23) {
        const __bf16* nx = w1l + (size_t)(kb + 1) * 6144;
#pragma unroll
        for (int j = 0; j < 3; ++j) bq[p ^ 1][j] = *(const bf16x8*)(nx + j * 512);
        aq[p ^ 1][0] = *(const bf16x8*)&xs[ln][(kb + 1) * 32 + q8];
        aq[p ^ 1][1] = *(const bf16x8*)&xs[16 + ln][(kb + 1) * 32 + q8];
      }
#pragma unroll
      for (int j = 0; j < 3; ++j) {
        c1[0][j] = __builtin_amdgcn_mfma_f32_16x16x32_bf16(aq[p][0], bq[p][j], c1[0][j], 0, 0, 0);
        c1[1][j] = __builtin_amdgcn_mfma_f32_16x16x32_bf16(aq[p][1], bq[p][j], c1[1][j], 0, 0, 0);
      }
    }
    // bias + exact gelu + gate scale -> hs (bf16)
#pragma unroll
    for (int j = 0; j < 3; ++j) {
      int col = wave * 48 + j * 16 + ln;
      float b1 = fc1_b[e * H_ + col];
#pragma unroll
      for (int m = 0; m < 2; ++m) {
#pragma unroll
        for (int r = 0; r < 4; ++r) {
          int row = m * 16 + q4 + r;
          float v = c1[m][j][r] + b1;
          float gl = 0.5f * v * (1.0f + erff(v * 0.70710678118f));
          hs[row][col] = (__bf16)(g * gl);
        }
      }
    }
    __syncthreads();

    // ---- GEMM2: y += h @ W2^T, waves split 768 into 4x192, K=192 (6 kb).
    // 12-step pipeline: step s -> kb=s/2, half=s&1, cols (half*6+j)*16.
    // bh[s&1] computed, bh[s&1^1] prefetched; av[kb&1] computed, av of kb+1
    // prefetched into av[(kb+1)&1] on odd steps (buffer not in use).
    const __bf16* w2l = pw2 + (size_t)e * (6 * 768 * 32)
                            + (size_t)(wave * 192 + ln) * 32 + q8;
    bf16x8 bh[2][6], av[2][2];
#pragma unroll
    for (int j = 0; j < 6; ++j) bh[0][j] = *(const bf16x8*)(w2l + j * 512);
    av[0][0] = *(const bf16x8*)&hs[ln][q8];
    av[0][1] = *(const bf16x8*)&hs[16 + ln][q8];
#pragma unroll
    for (int s = 0; s < 12; ++s) {
      const int kb = s >> 1;
      const int half = s & 1;
      const int p = s & 1;
      if (s < 11) {
        const int s2 = s + 1;
        const int kb2 = s2 >> 1;
        const int half2 = s2 & 1;
        const __bf16* src = w2l + (size_t)kb2 * 24576;
#pragma unroll
        for (int j = 0; j < 6; ++j)
          bh[p ^ 1][j] = *(const bf16x8*)(src + (half2 * 6 + j) * 512);
        if (half2 == 0) {   // new kb starts next step: load its A frags
          av[kb2 & 1][0] = *(const bf16x8*)&hs[ln][kb2 * 32 + q8];
          av[kb2 & 1][1] = *(const bf16x8*)&hs[16 + ln][kb2 * 32 + q8];
        }
      }
#pragma unroll
      for (int j = 0; j < 6; ++j) {
        const int jj = half * 6 + j;
        c2[0][jj] = __builtin_amdgcn_mfma_f32_16x16x32_bf16(av[kb & 1][0], bh[p][j], c2[0][jj], 0, 0, 0);
        c2[1][jj] = __builtin_amdgcn_mfma_f32_16x16x32_bf16(av[kb & 1][1], bh[p][j], c2[1][jj], 0, 0, 0);
      }
    }
    __syncthreads();   // protect hs before next expert overwrites
  }

  // epilogue: out = x + y (+ gate-weighted fc2_b)
  const float* xr = x + ((size_t)b * N_ + token0) * C_;
  float* outr = out + ((size_t)b * N_ + token0) * C_;
#pragma unroll
  for (int j = 0; j < 12; ++j) {
    int col = wave * 192 + j * 16 + ln;
    float b2t = gate_v[0] * fc2_b[e_idx[0] * C_ + col] +
                gate_v[1] * fc2_b[e_idx[1] * C_ + col];
#pragma unroll
    for (int m = 0; m < 2; ++m) {
#pragma unroll
      for (int r = 0; r < 4; ++r) {
        int row = m * 16 + q4 + r;
        size_t off = (size_t)row * C_ + col;
        outr[off] = xr[off] + c2[m][j][r] + b2t;
      }
    }
  }
}

// ---------------------------------------------------------------------------
extern "C" void kernel_launch(void* const* d_in, const int* in_sizes, int n_in,
                              void* d_out, int out_size, void* d_ws, size_t ws_size,
                              hipStream_t stream) {
  const float* x      = (const float*)d_in[0];
  const int*   task   = (const int*)d_in[1];
  const float* eps    = (const float*)d_in[2];
  const float* gate_w = (const float*)d_in[3];
  const float* fc1_w  = (const float*)d_in[4];
  const float* fc1_b  = (const float*)d_in[5];
  const float* fc2_w  = (const float*)d_in[6];
  const float* fc2_b  = (const float*)d_in[7];
  float* out = (float*)d_out;

  // workspace: pw1 | pw2 | gwT | sums  (~4.92 MB)
  const size_t nW = (size_t)E_ * H_ * C_;              // 1179648
  __bf16* pw1 = (__bf16*)d_ws;
  __bf16* pw2 = pw1 + nW;
  float* gwT  = (float*)((char*)d_ws + 2 * nW * sizeof(__bf16));
  float* sums = (float*)((char*)gwT + 4 * 16 * C_ * sizeof(float));

  hipMemsetAsync(sums, 0, B_ * E_ * sizeof(float), stream);
  prep_kernel<<<(nW / 4 + 255) / 256, 256, 0, stream>>>(fc1_w, fc2_w, gate_w,
                                                        pw1, pw2, gwT);
  gate_kernel<<<B_ * 64, 256, 0, stream>>>(x, task, eps, gwT, sums);
  expert_kernel<<<B_ * 32, 256, 0, stream>>>(x, pw1, pw2, fc1_b, fc2_b,
                                             sums, out);
}